// Round 4
// baseline (325.576 us; speedup 1.0000x reference)
//
#include <hip/hip_runtime.h>

// GridManifoldNetwork, round 17. Gather-wall model (fits R13/R15/R16 exactly):
// cost = active-lane requests; <=8B request = 1 unit, 16B = 2 units,
// exec-masked lanes = free. Chip wall ~0.232M units/us.
//   R13  8x8B          = 8 units  -> 72.5us
//   R15  4x16B + 2     = 10 units -> 90.6us (predicted exactly)
//   R16  8x4B          = 8 units  -> ~74us  (bytes model falsified)
// R17: bf16 tables (4B entries) make the x-corner pair {(i0^m),((i0+1)^m)}
// one aligned 8B load for EVEN i0 = 1 unit. 4 pair-loads (all lanes)
// + 4 masked 4B gathers (odd-i0 lanes, ~half) = 6 units vs 8.
// Predicted hash 74 -> ~56us each; total ~255-265us.
//
// Keep from R16 (verified): bf16 pk345 tables; A2/B2 level-2 pair tables +
// bf16 dense tables in dense_mlp (91->83us). Prep split: pk345 pack first
// (~3us, feeds hash), rest folded into hash3 tail blocks (R13 pattern).
//
// Levels: res=16,32,64,128,256,512; F=2; T=2^19; levels 3..5 hashed,
// & 0x7FFFF. Entry offsets: 0,4096,36864,299008,823296,1347584.
// Levels 0+1 (entries [0,36864)) staged to LDS as packed bf16x2 (144KB).

#define HP1 2654435761u
#define HP2 805459861u
#define HMASK ((1u << 19) - 1u)

typedef float v2f __attribute__((ext_vector_type(2)));

static __device__ __forceinline__ unsigned umin_(unsigned a, unsigned b) {
    return a < b ? a : b;
}

// bf16 round-to-nearest-even pack/unpack.
static __device__ __forceinline__ unsigned f2bf(float f) {
    unsigned u = __float_as_uint(f);
    return (u + 0x7fffu + ((u >> 16) & 1u)) >> 16;
}
static __device__ __forceinline__ float bf2f_lo(unsigned p) {
    return __uint_as_float((p & 0xffffu) << 16);
}
static __device__ __forceinline__ float bf2f_hi(unsigned p) {
    return __uint_as_float(p & 0xffff0000u);
}

static __device__ __forceinline__ v2f vmax0(v2f s) {
#if __has_builtin(__builtin_elementwise_max)
    return __builtin_elementwise_max(s, (v2f)0.0f);
#else
    v2f r; r.x = fmaxf(s.x, 0.0f); r.y = fmaxf(s.y, 0.0f); return r;
#endif
}

// Pack hash levels 3..5 (contiguous 1572864 float2 entries) to bf16x2.
// Must run before any hash kernel; ~3us.
__global__ __launch_bounds__(256) void prep345_kernel(
    const float2* __restrict__ gh, unsigned* __restrict__ pk345)
{
    const int stride = (int)gridDim.x * 256;
    for (int t = (int)blockIdx.x * 256 + threadIdx.x; t < 3 * 524288;
         t += stride) {
        const float2 e = gh[t];
        pk345[t] = f2bf(e.x) | (f2bf(e.y) << 16);
    }
}

// One hashed level, pair-gather form on bf16x2 table:
// 4 x 8B pair-loads (cover x-corner 0 always; x-corner 1 when i0 even)
// + 4 masked 4B gathers for odd-i0 lanes. 6 request-units/pt avg vs 8.
static __device__ __forceinline__ void hash_body(
    const float* __restrict__ x, const unsigned* __restrict__ tab,
    unsigned* __restrict__ feat, float scale, int N, int bid)
{
    const int gid = bid * 256 + threadIdx.x;
    if (gid >= N) return;

    const float px = __builtin_nontemporal_load(x + 3 * gid + 0);
    const float py = __builtin_nontemporal_load(x + 3 * gid + 1);
    const float pz = __builtin_nontemporal_load(x + 3 * gid + 2);

    const float p0 = fmaf((px + 1.0f) * 0.5f, scale, 0.5f);
    const float p1 = fmaf((py + 1.0f) * 0.5f, scale, 0.5f);
    const float p2 = fmaf((pz + 1.0f) * 0.5f, scale, 0.5f);
    const float g0 = floorf(p0), g1 = floorf(p1), g2 = floorf(p2);
    const float f0 = p0 - g0, f1 = p1 - g1, f2 = p2 - g2;
    const unsigned i0 = (unsigned)g0, i1 = (unsigned)g1, i2 = (unsigned)g2;

    const float wy[2] = {1.0f - f1, f1};
    const float wz[2] = {1.0f - f2, f2};
    const unsigned hy[2] = {i1 * HP1, (i1 + 1u) * HP1};
    const unsigned hz[2] = {i2 * HP2, (i2 + 1u) * HP2};

    unsigned m[4];
    float wyz[4];
    #pragma unroll
    for (int c = 0; c < 4; ++c) {
        m[c] = hy[c & 1] ^ hz[(c >> 1) & 1];
        wyz[c] = wy[c & 1] * wz[(c >> 1) & 1];
    }

    // Pair loads: q = {tab[e0&~1], tab[e0|1]}; partner is e0^1 which equals
    // ((i0+1)^m) exactly when i0 is even.
    unsigned v0[4], v1[4];
    #pragma unroll
    for (int c = 0; c < 4; ++c) {
        const unsigned e0 = (i0 ^ m[c]) & HMASK;
        const uint2 q = *reinterpret_cast<const uint2*>(tab + (e0 & ~1u));
        const bool hi = (e0 & 1u) != 0u;
        v0[c] = hi ? q.y : q.x;
        v1[c] = hi ? q.x : q.y;
    }
    if (i0 & 1u) {                 // odd i0: x-corner-1 not pair-adjacent
        #pragma unroll
        for (int c = 0; c < 4; ++c)
            v1[c] = tab[((i0 + 1u) ^ m[c]) & HMASK];
    }

    float a0 = 0.0f, a1 = 0.0f;
    const float wx0 = 1.0f - f0, wx1 = f0;
    #pragma unroll
    for (int c = 0; c < 4; ++c) {
        const float w0 = wyz[c] * wx0, w1 = wyz[c] * wx1;
        a0 = fmaf(w0, bf2f_lo(v0[c]), a0);
        a1 = fmaf(w0, bf2f_hi(v0[c]), a1);
        a0 = fmaf(w1, bf2f_lo(v1[c]), a0);
        a1 = fmaf(w1, bf2f_hi(v1[c]), a1);
    }
    __builtin_nontemporal_store(f2bf(a0) | (f2bf(a1) << 16), feat + gid);
}

// Hash level 3 + prep-rest folded into 64 tail blocks (R13 pattern):
// tail builds packed01 (LDS source), A2/B2 level-2 pair tables, wt.
__global__ __launch_bounds__(256) void hash3_prep_kernel(
    const float* __restrict__ x, const float2* __restrict__ gtab,
    const unsigned* __restrict__ pk345,
    unsigned* __restrict__ feat0, int N,
    float* __restrict__ wt, unsigned* __restrict__ packed,
    unsigned* __restrict__ A2, unsigned* __restrict__ B2,
    const float* __restrict__ W0, const float* __restrict__ b0,
    const float* __restrict__ W1, const float* __restrict__ b1)
{
    const int nh = (int)gridDim.x - 64;
    if ((int)blockIdx.x >= nh) {
        const int pb = (int)blockIdx.x - nh;   // 0..63
        for (int t = pb * 256 + threadIdx.x; t < 36864; t += 64 * 256) {
            const float2 e = gtab[t];
            packed[t] = f2bf(e.x) | (f2bf(e.y) << 16);
        }
        const float2* g2 = gtab + 36864u;      // level 2, 64^3 entries
        for (int t = pb * 256 + threadIdx.x; t < 262144; t += 64 * 256) {
            const float2 e = g2[t];
            A2[t] = f2bf(e.x) | (f2bf(e.y) << 16);
            const int xc = t & 63;
            const float2 en = g2[(xc == 63) ? t : t + 1];
            B2[t] = f2bf(en.x) | (f2bf(en.y) << 16);
        }
        if (pb == 0) {
            for (int t = threadIdx.x; t < 1024; t += 256) {
                const int j = t >> 4, i = t & 15;
                wt[t] = (i == 15) ? b0[j] : W0[i * 64 + j];
            }
            if (threadIdx.x < 64) wt[1024 + threadIdx.x] = W1[threadIdx.x];
            if (threadIdx.x == 0) wt[1088] = b1[0];
        }
        return;
    }
    hash_body(x, pk345, feat0, 127.0f, N, (int)blockIdx.x);
}

__global__ __launch_bounds__(256) void hash_level_kernel(
    const float* __restrict__ x, const unsigned* __restrict__ tab,
    unsigned* __restrict__ feat, float scale, int N)
{
    hash_body(x, tab, feat, scale, N, (int)blockIdx.x);
}

// Dense trilinear level from global fp32 float2 (level-1 fallback only).
static __device__ __forceinline__ void dense_level(
    const float2* __restrict__ tab, unsigned res,
    float xn0, float xn1, float xn2, float& o0, float& o1)
{
    const float scale = (float)(res - 1);
    const float p0 = fmaf(xn0, scale, 0.5f);
    const float p1 = fmaf(xn1, scale, 0.5f);
    const float p2 = fmaf(xn2, scale, 0.5f);
    const float g0 = floorf(p0), g1 = floorf(p1), g2 = floorf(p2);
    const float f0 = p0 - g0, f1 = p1 - g1, f2 = p2 - g2;
    const unsigned i0 = (unsigned)g0, i1 = (unsigned)g1, i2 = (unsigned)g2;

    const unsigned rm1 = res - 1u;
    const unsigned cx[2] = {umin_(i0, rm1), umin_(i0 + 1u, rm1)};
    const unsigned cy[2] = {umin_(i1, rm1) * res, umin_(i1 + 1u, rm1) * res};
    const unsigned cz[2] = {umin_(i2, rm1) * res * res,
                            umin_(i2 + 1u, rm1) * res * res};
    const float wx[2] = {1.0f - f0, f0};
    const float wy[2] = {1.0f - f1, f1};
    const float wz[2] = {1.0f - f2, f2};

    float a0 = 0.0f, a1 = 0.0f;
    #pragma unroll
    for (int c = 0; c < 8; ++c) {
        const int bx = c & 1, by = (c >> 1) & 1, bz = (c >> 2) & 1;
        const unsigned idx = cx[bx] + cy[by] + cz[bz];
        const float w = wx[bx] * wy[by] * wz[bz];
        const float2 v = tab[idx];
        a0 = fmaf(w, v.x, a0);
        a1 = fmaf(w, v.y, a1);
    }
    o0 = a0;
    o1 = a1;
}

// Dense level 2 (res=64) from packed pair tables: every x-corner pair is
// one aligned 8B load (A2 even base-x, B2 shifted copy for odd; clamp
// baked into B2). 4 request-units/pt.
static __device__ __forceinline__ void dense_level2_pk(
    const unsigned* __restrict__ A2, const unsigned* __restrict__ B2,
    float xn0, float xn1, float xn2, float& o0, float& o1)
{
    const float p0 = fmaf(xn0, 63.0f, 0.5f);
    const float p1 = fmaf(xn1, 63.0f, 0.5f);
    const float p2 = fmaf(xn2, 63.0f, 0.5f);
    const float g0 = floorf(p0), g1 = floorf(p1), g2 = floorf(p2);
    const float f0 = p0 - g0, f1 = p1 - g1, f2 = p2 - g2;
    const unsigned i0 = (unsigned)g0, i1 = (unsigned)g1, i2 = (unsigned)g2;

    const unsigned cx0 = umin_(i0, 63u);
    const unsigned cy[2] = {umin_(i1, 63u) * 64u, umin_(i1 + 1u, 63u) * 64u};
    const unsigned cz[2] = {umin_(i2, 63u) * 4096u,
                            umin_(i2 + 1u, 63u) * 4096u};
    const float wx[2] = {1.0f - f0, f0};
    const float wy[2] = {1.0f - f1, f1};
    const float wz[2] = {1.0f - f2, f2};

    const unsigned* tsel = (cx0 & 1u) ? B2 : A2;
    const unsigned xb = cx0 & ~1u;

    float a0 = 0.0f, a1 = 0.0f;
    #pragma unroll
    for (int c = 0; c < 4; ++c) {
        const int by = c & 1, bz = (c >> 1) & 1;
        const uint2 q = *reinterpret_cast<const uint2*>(
            tsel + xb + cy[by] + cz[bz]);
        const float wyz = wy[by] * wz[bz];
        const float w0 = wyz * wx[0], w1 = wyz * wx[1];
        a0 = fmaf(w0, bf2f_lo(q.x), a0);
        a1 = fmaf(w0, bf2f_hi(q.x), a1);
        a0 = fmaf(w1, bf2f_lo(q.y), a0);
        a1 = fmaf(w1, bf2f_hi(q.y), a1);
    }
    o0 = a0;
    o1 = a1;
}

// Dense trilinear level from LDS-resident packed bf16x2 table (R11 form).
static __device__ __forceinline__ void dense_level_lds(
    const unsigned* __restrict__ sPk, unsigned off, unsigned res,
    float xn0, float xn1, float xn2, float& o0, float& o1)
{
    const float scale = (float)(res - 1);
    const float p0 = fmaf(xn0, scale, 0.5f);
    const float p1 = fmaf(xn1, scale, 0.5f);
    const float p2 = fmaf(xn2, scale, 0.5f);
    const float g0 = floorf(p0), g1 = floorf(p1), g2 = floorf(p2);
    const float f0 = p0 - g0, f1 = p1 - g1, f2 = p2 - g2;
    const unsigned i0 = (unsigned)g0, i1 = (unsigned)g1, i2 = (unsigned)g2;

    const unsigned rm1 = res - 1u;
    const unsigned cx[2] = {umin_(i0, rm1), umin_(i0 + 1u, rm1)};
    const unsigned cy[2] = {umin_(i1, rm1) * res, umin_(i1 + 1u, rm1) * res};
    const unsigned cz[2] = {umin_(i2, rm1) * res * res,
                            umin_(i2 + 1u, rm1) * res * res};
    const float wx[2] = {1.0f - f0, f0};
    const float wy[2] = {1.0f - f1, f1};
    const float wz[2] = {1.0f - f2, f2};

    float a0 = 0.0f, a1 = 0.0f;
    #pragma unroll
    for (int c = 0; c < 8; ++c) {
        const int bx = c & 1, by = (c >> 1) & 1, bz = (c >> 2) & 1;
        const unsigned p = sPk[off + cx[bx] + cy[by] + cz[bz]];
        const float w = wx[bx] * wy[by] * wz[bz];
        a0 = fmaf(w, bf2f_lo(p), a0);
        a1 = fmaf(w, bf2f_hi(p), a1);
    }
    o0 = a0;
    o1 = a1;
}

// Dense levels + MLP, 4 points/thread (R11 form, R16-verified 83us).
template<int BLOCK, bool L1LDS>
__global__ __launch_bounds__(BLOCK, 4) void dense_mlp_kernel(
    const float* __restrict__ x,
    const float* __restrict__ grid,
    const unsigned* __restrict__ feat,   // [3][N] packed bf16x2
    const float* __restrict__ wt,        // 1089 floats
    const unsigned* __restrict__ packed, // 36864 bf16x2 words (levels 0+1)
    const unsigned* __restrict__ A2,     // level-2 packed (identity)
    const unsigned* __restrict__ B2,     // level-2 packed (x+1, clamped)
    float* __restrict__ out, int N)
{
    extern __shared__ unsigned sPk[];
    const int tid = threadIdx.x;

    const int nstage = L1LDS ? 36864 : 4096;
    for (int t = tid; t < nstage; t += BLOCK)
        sPk[t] = packed[t];
    __syncthreads();

    const int base = blockIdx.x * (BLOCK * 4) + tid;
    const float2* gtab = (const float2*)grid;

    // hp[p][i] = {feature i of point 2p, feature i of point 2p+1}
    v2f hp[2][16];

    #pragma unroll
    for (int k = 0; k < 4; ++k) {
        const int g = base + BLOCK * k;
        const int gs = (g < N) ? g : 0;
        const int p = k >> 1, lane = k & 1;

        const float px = __builtin_nontemporal_load(x + 3 * gs + 0);
        const float py = __builtin_nontemporal_load(x + 3 * gs + 1);
        const float pz = __builtin_nontemporal_load(x + 3 * gs + 2);
        const float xn0 = (px + 1.0f) * 0.5f;
        const float xn1 = (py + 1.0f) * 0.5f;
        const float xn2 = (pz + 1.0f) * 0.5f;

        hp[p][0][lane] = px; hp[p][1][lane] = py; hp[p][2][lane] = pz;
        hp[p][15][lane] = 1.0f;

        float t3, t4, t5, t6, t7, t8;
        dense_level_lds(sPk, 0u, 16u, xn0, xn1, xn2, t3, t4);
        if (L1LDS)
            dense_level_lds(sPk, 4096u, 32u, xn0, xn1, xn2, t5, t6);
        else
            dense_level(gtab + 4096u, 32u, xn0, xn1, xn2, t5, t6);
        dense_level2_pk(A2, B2, xn0, xn1, xn2, t7, t8);
        hp[p][3][lane] = t3; hp[p][4][lane] = t4;
        hp[p][5][lane] = t5; hp[p][6][lane] = t6;
        hp[p][7][lane] = t7; hp[p][8][lane] = t8;

        #pragma unroll
        for (int l = 0; l < 3; ++l) {
            const unsigned pk = __builtin_nontemporal_load(
                feat + (size_t)l * N + gs);
            hp[p][9 + 2 * l][lane]  = bf2f_lo(pk);
            hp[p][10 + 2 * l][lane] = bf2f_hi(pk);
        }
    }

    // MLP: out = relu(h @ W0 + b0) @ W1 + b1 (bias folded via h[15]=1).
    const float b1v = wt[1088];
    v2f o2[2];
    o2[0] = (v2f)b1v; o2[1] = (v2f)b1v;

    #pragma unroll 4
    for (int j = 0; j < 64; ++j) {
        float r[16];
        #pragma unroll
        for (int i = 0; i < 16; ++i)
            r[i] = wt[j * 16 + i];          // uniform -> s_load (SMEM pipe)
        const float w1j = wt[1024 + j];
        #pragma unroll
        for (int p = 0; p < 2; ++p) {
            v2f s = (v2f)0.0f;
            #pragma unroll
            for (int i = 0; i < 16; ++i)
                s = hp[p][i] * r[i] + s;     // v_pk_fma_f32
            s = vmax0(s);
            o2[p] = s * w1j + o2[p];
        }
    }

    #pragma unroll
    for (int k = 0; k < 4; ++k) {
        const int g = base + BLOCK * k;
        if (g < N)
            __builtin_nontemporal_store(o2[k >> 1][k & 1], out + g);
    }
}

extern "C" void kernel_launch(void* const* d_in, const int* in_sizes, int n_in,
                              void* d_out, int out_size, void* d_ws, size_t ws_size,
                              hipStream_t stream) {
    const float* x    = (const float*)d_in[0];
    const float* grid = (const float*)d_in[1];
    const float* W0   = (const float*)d_in[2];
    const float* b0   = (const float*)d_in[3];
    const float* W1   = (const float*)d_in[4];
    const float* b1   = (const float*)d_in[5];
    float* out = (float*)d_out;

    const int N = in_sizes[0] / 3;
    const int blocks1 = (N + 255) / 256;

    const float2* gtab = (const float2*)grid;

    auto align256 = [](size_t v) { return (v + 255) & ~(size_t)255; };
    size_t off = 0;
    const size_t feat_off = off; off += align256((size_t)3 * N * 4);
    const size_t wt_off   = off; off += align256(1089 * 4);
    const size_t pk_off   = off; off += align256(36864 * 4);
    const size_t a2_off   = off; off += align256(262144 * 4);
    const size_t b2_off   = off; off += align256(262144 * 4);
    const size_t h_off    = off; off += align256((size_t)3 * 524288 * 4);
    (void)ws_size;

    unsigned* feat   = (unsigned*)((char*)d_ws + feat_off);
    float*    wt     = (float*)((char*)d_ws + wt_off);
    unsigned* packed = (unsigned*)((char*)d_ws + pk_off);
    unsigned* A2     = (unsigned*)((char*)d_ws + a2_off);
    unsigned* B2     = (unsigned*)((char*)d_ws + b2_off);
    unsigned* pk345  = (unsigned*)((char*)d_ws + h_off);

    // Pack hash tables 3..5 to bf16 (feeds all hash kernels; ~3us).
    prep345_kernel<<<512, 256, 0, stream>>>(gtab + 299008u, pk345);

    // Hash level 3 + prep-rest (64 tail blocks: packed01, A2/B2, wt).
    hash3_prep_kernel<<<blocks1 + 64, 256, 0, stream>>>(
        x, gtab, pk345 + (size_t)0 * 524288, feat + (size_t)0 * N, N,
        wt, packed, A2, B2, W0, b0, W1, b1);
    hash_level_kernel<<<blocks1, 256, 0, stream>>>(
        x, pk345 + (size_t)1 * 524288, feat + (size_t)1 * N, 255.0f, N);
    hash_level_kernel<<<blocks1, 256, 0, stream>>>(
        x, pk345 + (size_t)2 * 524288, feat + (size_t)2 * N, 511.0f, N);

    // Gate the 144KB-LDS path on what the runtime actually permits
    // (host-side queries: deterministic, graph-capture-safe).
    const size_t bigShm = 36864u * 4u;           // 147456 B
    const void* bigK =
        reinterpret_cast<const void*>(&dense_mlp_kernel<1024, true>);
    (void)hipFuncSetAttribute(bigK,
        hipFuncAttributeMaxDynamicSharedMemorySize, (int)bigShm);
    bool big = false;
    hipFuncAttributes fa{};
    if (hipFuncGetAttributes(&fa, bigK) == hipSuccess)
        big = ((size_t)fa.maxDynamicSharedSizeBytes >= bigShm);

    if (big) {
        const int blocksB = (N + 4095) / 4096;   // 1024 thr x 4 pts
        dense_mlp_kernel<1024, true><<<blocksB, 1024, bigShm, stream>>>(
            x, (const float*)grid, feat, wt, packed, A2, B2, out, N);
    } else {
        const int blocksF = (N + 1023) / 1024;   // 256 thr x 4 pts
        dense_mlp_kernel<256, false><<<blocksF, 256, 4096u * 4u, stream>>>(
            x, (const float*)grid, feat, wt, packed, A2, B2, out, N);
    }
}

// Round 5
// 308.160 us; speedup vs baseline: 1.0565x; 1.0565x over previous
//
#include <hip/hip_runtime.h>

// GridManifoldNetwork, round 18. Request-shaping on the hash wall is
// EXHAUSTED: R13 8x8B=72.5us, R15 pair16B=90.6, R16 8x4B=74, R17 pair8B=79.
// Every model (bytes/req-count/req-units) falsified by at least one point;
// empirical truth: ~72.5us/level minimum at R13's plain form. -> Revert hash
// to R13 exactly (fp32 table, 8x8B gathers), drop pk345 pack, fold all prep
// into hash3 tail blocks (R12-verified pattern).
//
// New lever: dense_mlp phase serialization. 83us = MLP VALU 46 + gather 36
// (sum matches measured => serial; VALUBusy 56%, HBM 6%). Pipeline: issue
// ALL global loads (x + 4 level-2 pair-gathers/pt + 3 feat/pt, 4 pts, ~28
// outstanding VMEM) BEFORE any consumption; then per-pair build+MLP. L2
// latency drains under LDS trilerps + first pair's MLP. Coarse issue/consume
// split (G7), not instruction scheduling (R3/R12 falsified that).
//
// Predicted: hash ~72.5 each; dense_mlp 83 -> 62-70 (VALUBusy -> 65-75%,
// VGPR ~100-120); total ~285-295. Falsifier: dense_mlp >=80 with VGPR in
// budget -> convoy theory wrong, attack VALU fat next.
//
// Levels: res=16,32,64,128,256,512; F=2; T=2^19; levels 3..5 hashed,
// & 0x7FFFF. Entry offsets: 0,4096,36864,299008,823296,1347584.
// Levels 0+1 (entries [0,36864)) staged to LDS as packed bf16x2 (144KB).
// Level 2 via A2/B2 bf16 pair tables (R15-verified dense win).

#define HP1 2654435761u
#define HP2 805459861u
#define HMASK ((1u << 19) - 1u)

typedef float v2f __attribute__((ext_vector_type(2)));

static __device__ __forceinline__ unsigned umin_(unsigned a, unsigned b) {
    return a < b ? a : b;
}

// bf16 round-to-nearest-even pack/unpack.
static __device__ __forceinline__ unsigned f2bf(float f) {
    unsigned u = __float_as_uint(f);
    return (u + 0x7fffu + ((u >> 16) & 1u)) >> 16;
}
static __device__ __forceinline__ float bf2f_lo(unsigned p) {
    return __uint_as_float((p & 0xffffu) << 16);
}
static __device__ __forceinline__ float bf2f_hi(unsigned p) {
    return __uint_as_float(p & 0xffff0000u);
}

static __device__ __forceinline__ v2f vmax0(v2f s) {
#if __has_builtin(__builtin_elementwise_max)
    return __builtin_elementwise_max(s, (v2f)0.0f);
#else
    v2f r; r.x = fmaxf(s.x, 0.0f); r.y = fmaxf(s.y, 0.0f); return r;
#endif
}

// One hashed-level point block: R13 form verbatim. 8 divergent 8B gathers
// from the fp32 float2 table + trilerp + bf16 pack. 72.5us/level proven.
static __device__ __forceinline__ void hash_body(
    const float* __restrict__ x, const float2* __restrict__ tab,
    unsigned* __restrict__ feat, float scale, int N, int bid)
{
    const int gid = bid * 256 + threadIdx.x;
    if (gid >= N) return;

    const float px = __builtin_nontemporal_load(x + 3 * gid + 0);
    const float py = __builtin_nontemporal_load(x + 3 * gid + 1);
    const float pz = __builtin_nontemporal_load(x + 3 * gid + 2);

    const float p0 = fmaf((px + 1.0f) * 0.5f, scale, 0.5f);
    const float p1 = fmaf((py + 1.0f) * 0.5f, scale, 0.5f);
    const float p2 = fmaf((pz + 1.0f) * 0.5f, scale, 0.5f);
    const float g0 = floorf(p0), g1 = floorf(p1), g2 = floorf(p2);
    const float f0 = p0 - g0, f1 = p1 - g1, f2 = p2 - g2;
    const unsigned i0 = (unsigned)g0, i1 = (unsigned)g1, i2 = (unsigned)g2;

    const float wx[2] = {1.0f - f0, f0};
    const float wy[2] = {1.0f - f1, f1};
    const float wz[2] = {1.0f - f2, f2};
    const unsigned hx[2] = {i0, i0 + 1u};
    const unsigned hy[2] = {i1 * HP1, (i1 + 1u) * HP1};
    const unsigned hz[2] = {i2 * HP2, (i2 + 1u) * HP2};

    unsigned idx[8];
    float w[8];
    #pragma unroll
    for (int c = 0; c < 8; ++c) {
        const int bx = c & 1, by = (c >> 1) & 1, bz = (c >> 2) & 1;
        idx[c] = (hx[bx] ^ hy[by] ^ hz[bz]) & HMASK;
        w[c] = wx[bx] * wy[by] * wz[bz];
    }
    float2 v[8];
    #pragma unroll
    for (int c = 0; c < 8; ++c) v[c] = tab[idx[c]];

    float a0 = 0.0f, a1 = 0.0f;
    #pragma unroll
    for (int c = 0; c < 8; ++c) {
        a0 = fmaf(w[c], v[c].x, a0);
        a1 = fmaf(w[c], v[c].y, a1);
    }
    __builtin_nontemporal_store(f2bf(a0) | (f2bf(a1) << 16), feat + gid);
}

// Hash level 3 + all prep folded into 64 tail blocks (R12-verified):
// tail builds packed01 (LDS source), A2/B2 level-2 pair tables, wt.
__global__ __launch_bounds__(256) void hash3_prep_kernel(
    const float* __restrict__ x, const float2* __restrict__ gtab,
    unsigned* __restrict__ feat0, int N,
    float* __restrict__ wt, unsigned* __restrict__ packed,
    unsigned* __restrict__ A2, unsigned* __restrict__ B2,
    const float* __restrict__ W0, const float* __restrict__ b0,
    const float* __restrict__ W1, const float* __restrict__ b1)
{
    const int nh = (int)gridDim.x - 64;
    if ((int)blockIdx.x >= nh) {
        const int pb = (int)blockIdx.x - nh;   // 0..63
        for (int t = pb * 256 + threadIdx.x; t < 36864; t += 64 * 256) {
            const float2 e = gtab[t];
            packed[t] = f2bf(e.x) | (f2bf(e.y) << 16);
        }
        const float2* g2 = gtab + 36864u;      // level 2, 64^3 entries
        for (int t = pb * 256 + threadIdx.x; t < 262144; t += 64 * 256) {
            const float2 e = g2[t];
            A2[t] = f2bf(e.x) | (f2bf(e.y) << 16);
            const int xc = t & 63;
            const float2 en = g2[(xc == 63) ? t : t + 1];
            B2[t] = f2bf(en.x) | (f2bf(en.y) << 16);
        }
        if (pb == 0) {
            for (int t = threadIdx.x; t < 1024; t += 256) {
                const int j = t >> 4, i = t & 15;
                wt[t] = (i == 15) ? b0[j] : W0[i * 64 + j];
            }
            if (threadIdx.x < 64) wt[1024 + threadIdx.x] = W1[threadIdx.x];
            if (threadIdx.x == 0) wt[1088] = b1[0];
        }
        return;
    }
    hash_body(x, gtab + 299008u, feat0, 127.0f, N, (int)blockIdx.x);
}

__global__ __launch_bounds__(256) void hash_level_kernel(
    const float* __restrict__ x, const float2* __restrict__ tab,
    unsigned* __restrict__ feat, float scale, int N)
{
    hash_body(x, tab, feat, scale, N, (int)blockIdx.x);
}

// Dense trilinear level from global fp32 float2 (level-1 fallback only).
static __device__ __forceinline__ void dense_level(
    const float2* __restrict__ tab, unsigned res,
    float xn0, float xn1, float xn2, float& o0, float& o1)
{
    const float scale = (float)(res - 1);
    const float p0 = fmaf(xn0, scale, 0.5f);
    const float p1 = fmaf(xn1, scale, 0.5f);
    const float p2 = fmaf(xn2, scale, 0.5f);
    const float g0 = floorf(p0), g1 = floorf(p1), g2 = floorf(p2);
    const float f0 = p0 - g0, f1 = p1 - g1, f2 = p2 - g2;
    const unsigned i0 = (unsigned)g0, i1 = (unsigned)g1, i2 = (unsigned)g2;

    const unsigned rm1 = res - 1u;
    const unsigned cx[2] = {umin_(i0, rm1), umin_(i0 + 1u, rm1)};
    const unsigned cy[2] = {umin_(i1, rm1) * res, umin_(i1 + 1u, rm1) * res};
    const unsigned cz[2] = {umin_(i2, rm1) * res * res,
                            umin_(i2 + 1u, rm1) * res * res};
    const float wx[2] = {1.0f - f0, f0};
    const float wy[2] = {1.0f - f1, f1};
    const float wz[2] = {1.0f - f2, f2};

    float a0 = 0.0f, a1 = 0.0f;
    #pragma unroll
    for (int c = 0; c < 8; ++c) {
        const int bx = c & 1, by = (c >> 1) & 1, bz = (c >> 2) & 1;
        const unsigned idx = cx[bx] + cy[by] + cz[bz];
        const float w = wx[bx] * wy[by] * wz[bz];
        const float2 v = tab[idx];
        a0 = fmaf(w, v.x, a0);
        a1 = fmaf(w, v.y, a1);
    }
    o0 = a0;
    o1 = a1;
}

// Dense trilinear level from LDS-resident packed bf16x2 table (R11 form).
static __device__ __forceinline__ void dense_level_lds(
    const unsigned* __restrict__ sPk, unsigned off, unsigned res,
    float xn0, float xn1, float xn2, float& o0, float& o1)
{
    const float scale = (float)(res - 1);
    const float p0 = fmaf(xn0, scale, 0.5f);
    const float p1 = fmaf(xn1, scale, 0.5f);
    const float p2 = fmaf(xn2, scale, 0.5f);
    const float g0 = floorf(p0), g1 = floorf(p1), g2 = floorf(p2);
    const float f0 = p0 - g0, f1 = p1 - g1, f2 = p2 - g2;
    const unsigned i0 = (unsigned)g0, i1 = (unsigned)g1, i2 = (unsigned)g2;

    const unsigned rm1 = res - 1u;
    const unsigned cx[2] = {umin_(i0, rm1), umin_(i0 + 1u, rm1)};
    const unsigned cy[2] = {umin_(i1, rm1) * res, umin_(i1 + 1u, rm1) * res};
    const unsigned cz[2] = {umin_(i2, rm1) * res * res,
                            umin_(i2 + 1u, rm1) * res * res};
    const float wx[2] = {1.0f - f0, f0};
    const float wy[2] = {1.0f - f1, f1};
    const float wz[2] = {1.0f - f2, f2};

    float a0 = 0.0f, a1 = 0.0f;
    #pragma unroll
    for (int c = 0; c < 8; ++c) {
        const int bx = c & 1, by = (c >> 1) & 1, bz = (c >> 2) & 1;
        const unsigned p = sPk[off + cx[bx] + cy[by] + cz[bz]];
        const float w = wx[bx] * wy[by] * wz[bz];
        a0 = fmaf(w, bf2f_lo(p), a0);
        a1 = fmaf(w, bf2f_hi(p), a1);
    }
    o0 = a0;
    o1 = a1;
}

// ---- dense_mlp pipeline pieces ----

// Issue phase: all global loads for one point (x, 4 level-2 pair loads,
// 3 feat words). No consumption -> loads stay outstanding.
static __device__ __forceinline__ void issue_point(
    const float* __restrict__ x, const unsigned* __restrict__ A2,
    const unsigned* __restrict__ B2, const unsigned* __restrict__ feat,
    int gs, int N, float& px, float& py, float& pz,
    uint2* __restrict__ q, unsigned* __restrict__ fw)
{
    px = __builtin_nontemporal_load(x + 3 * gs + 0);
    py = __builtin_nontemporal_load(x + 3 * gs + 1);
    pz = __builtin_nontemporal_load(x + 3 * gs + 2);
    const float xn0 = (px + 1.0f) * 0.5f;
    const float xn1 = (py + 1.0f) * 0.5f;
    const float xn2 = (pz + 1.0f) * 0.5f;
    const float p0 = fmaf(xn0, 63.0f, 0.5f);
    const float p1 = fmaf(xn1, 63.0f, 0.5f);
    const float p2 = fmaf(xn2, 63.0f, 0.5f);
    const unsigned i0 = (unsigned)floorf(p0);
    const unsigned i1 = (unsigned)floorf(p1);
    const unsigned i2 = (unsigned)floorf(p2);
    const unsigned cx0 = umin_(i0, 63u);
    const unsigned cy0 = umin_(i1, 63u) * 64u, cy1 = umin_(i1 + 1u, 63u) * 64u;
    const unsigned cz0 = umin_(i2, 63u) * 4096u,
                   cz1 = umin_(i2 + 1u, 63u) * 4096u;
    const unsigned* tsel = (cx0 & 1u) ? B2 : A2;   // q.x=corner0, q.y=corner1
    const unsigned xb = cx0 & ~1u;
    q[0] = *reinterpret_cast<const uint2*>(tsel + xb + cy0 + cz0);
    q[1] = *reinterpret_cast<const uint2*>(tsel + xb + cy1 + cz0);
    q[2] = *reinterpret_cast<const uint2*>(tsel + xb + cy0 + cz1);
    q[3] = *reinterpret_cast<const uint2*>(tsel + xb + cy1 + cz1);
    fw[0] = __builtin_nontemporal_load(feat + (size_t)0 * N + gs);
    fw[1] = __builtin_nontemporal_load(feat + (size_t)1 * N + gs);
    fw[2] = __builtin_nontemporal_load(feat + (size_t)2 * N + gs);
}

// Build phase: LDS trilerps (levels 0/1) + combine raw level-2 + unpack
// feat -> one lane of the pair's hp[16].
template<bool L1LDS>
static __device__ __forceinline__ void build_point(
    const unsigned* __restrict__ sPk, const float2* __restrict__ gtab,
    float px, float py, float pz,
    const uint2* __restrict__ q, const unsigned* __restrict__ fw,
    v2f* __restrict__ hp, int lane)
{
    const float xn0 = (px + 1.0f) * 0.5f;
    const float xn1 = (py + 1.0f) * 0.5f;
    const float xn2 = (pz + 1.0f) * 0.5f;
    hp[0][lane] = px; hp[1][lane] = py; hp[2][lane] = pz;
    hp[15][lane] = 1.0f;

    float t3, t4, t5, t6;
    dense_level_lds(sPk, 0u, 16u, xn0, xn1, xn2, t3, t4);
    if (L1LDS)
        dense_level_lds(sPk, 4096u, 32u, xn0, xn1, xn2, t5, t6);
    else
        dense_level(gtab + 4096u, 32u, xn0, xn1, xn2, t5, t6);
    hp[3][lane] = t3; hp[4][lane] = t4;
    hp[5][lane] = t5; hp[6][lane] = t6;

    // Level-2 combine (weights recomputed; q loaded in issue phase).
    const float p0 = fmaf(xn0, 63.0f, 0.5f);
    const float p1 = fmaf(xn1, 63.0f, 0.5f);
    const float p2 = fmaf(xn2, 63.0f, 0.5f);
    const float f0 = p0 - floorf(p0);
    const float f1 = p1 - floorf(p1);
    const float f2 = p2 - floorf(p2);
    const float wx0 = 1.0f - f0, wx1 = f0;
    const float wy[2] = {1.0f - f1, f1};
    const float wz[2] = {1.0f - f2, f2};
    float a0 = 0.0f, a1 = 0.0f;
    #pragma unroll
    for (int c = 0; c < 4; ++c) {
        const float wyz = wy[c & 1] * wz[(c >> 1) & 1];
        const float w0 = wyz * wx0, w1 = wyz * wx1;
        a0 = fmaf(w0, bf2f_lo(q[c].x), a0);
        a1 = fmaf(w0, bf2f_hi(q[c].x), a1);
        a0 = fmaf(w1, bf2f_lo(q[c].y), a0);
        a1 = fmaf(w1, bf2f_hi(q[c].y), a1);
    }
    hp[7][lane] = a0; hp[8][lane] = a1;

    #pragma unroll
    for (int l = 0; l < 3; ++l) {
        hp[9 + 2 * l][lane]  = bf2f_lo(fw[l]);
        hp[10 + 2 * l][lane] = bf2f_hi(fw[l]);
    }
}

// MLP for one 2-point pair: R11 form verbatim (weights via SMEM pipe,
// v_pk_fma over v2f pairs).
static __device__ __forceinline__ v2f mlp_pair(
    const float* __restrict__ wt, const v2f* __restrict__ hp)
{
    v2f o2 = (v2f)wt[1088];
    #pragma unroll 4
    for (int j = 0; j < 64; ++j) {
        float r[16];
        #pragma unroll
        for (int i = 0; i < 16; ++i)
            r[i] = wt[j * 16 + i];          // uniform -> s_load (SMEM pipe)
        const float w1j = wt[1024 + j];
        v2f s = (v2f)0.0f;
        #pragma unroll
        for (int i = 0; i < 16; ++i)
            s = hp[i] * r[i] + s;            // v_pk_fma_f32
        s = vmax0(s);
        o2 = s * w1j + o2;
    }
    return o2;
}

// Dense levels + MLP, 4 points/thread, SOFTWARE-PIPELINED: issue all
// global loads first (28 outstanding VMEM), then per-pair build+MLP.
template<int BLOCK, bool L1LDS>
__global__ __launch_bounds__(BLOCK, 4) void dense_mlp_kernel(
    const float* __restrict__ x,
    const float* __restrict__ grid,
    const unsigned* __restrict__ feat,   // [3][N] packed bf16x2
    const float* __restrict__ wt,        // 1089 floats
    const unsigned* __restrict__ packed, // 36864 bf16x2 words (levels 0+1)
    const unsigned* __restrict__ A2,     // level-2 packed (identity)
    const unsigned* __restrict__ B2,     // level-2 packed (x+1, clamped)
    float* __restrict__ out, int N)
{
    extern __shared__ unsigned sPk[];
    const int tid = threadIdx.x;

    const int nstage = L1LDS ? 36864 : 4096;
    for (int t = tid; t < nstage; t += BLOCK)
        sPk[t] = packed[t];
    __syncthreads();

    const int base = blockIdx.x * (BLOCK * 4) + tid;
    const float2* gtab = (const float2*)grid;

    // Phase A: issue all global loads for 4 points.
    float px[4], py[4], pz[4];
    uint2 q2[4][4];
    unsigned fw[4][3];
    #pragma unroll
    for (int k = 0; k < 4; ++k) {
        const int g = base + BLOCK * k;
        const int gs = (g < N) ? g : 0;
        issue_point(x, A2, B2, feat, gs, N,
                    px[k], py[k], pz[k], q2[k], fw[k]);
    }

    // Phase B/C: per-pair build + MLP (pair1's loads drain under pair0's
    // build+MLP VALU).
    v2f hp[16];
    build_point<L1LDS>(sPk, gtab, px[0], py[0], pz[0], q2[0], fw[0], hp, 0);
    build_point<L1LDS>(sPk, gtab, px[1], py[1], pz[1], q2[1], fw[1], hp, 1);
    const v2f oA = mlp_pair(wt, hp);
    build_point<L1LDS>(sPk, gtab, px[2], py[2], pz[2], q2[2], fw[2], hp, 0);
    build_point<L1LDS>(sPk, gtab, px[3], py[3], pz[3], q2[3], fw[3], hp, 1);
    const v2f oB = mlp_pair(wt, hp);

    #pragma unroll
    for (int k = 0; k < 4; ++k) {
        const int g = base + BLOCK * k;
        if (g < N) {
            const float o = (k < 2) ? oA[k & 1] : oB[k & 1];
            __builtin_nontemporal_store(o, out + g);
        }
    }
}

extern "C" void kernel_launch(void* const* d_in, const int* in_sizes, int n_in,
                              void* d_out, int out_size, void* d_ws, size_t ws_size,
                              hipStream_t stream) {
    const float* x    = (const float*)d_in[0];
    const float* grid = (const float*)d_in[1];
    const float* W0   = (const float*)d_in[2];
    const float* b0   = (const float*)d_in[3];
    const float* W1   = (const float*)d_in[4];
    const float* b1   = (const float*)d_in[5];
    float* out = (float*)d_out;

    const int N = in_sizes[0] / 3;
    const int blocks1 = (N + 255) / 256;

    const float2* gtab = (const float2*)grid;

    auto align256 = [](size_t v) { return (v + 255) & ~(size_t)255; };
    size_t off = 0;
    const size_t feat_off = off; off += align256((size_t)3 * N * 4);
    const size_t wt_off   = off; off += align256(1089 * 4);
    const size_t pk_off   = off; off += align256(36864 * 4);
    const size_t a2_off   = off; off += align256(262144 * 4);
    const size_t b2_off   = off; off += align256(262144 * 4);
    (void)ws_size;

    unsigned* feat   = (unsigned*)((char*)d_ws + feat_off);
    float*    wt     = (float*)((char*)d_ws + wt_off);
    unsigned* packed = (unsigned*)((char*)d_ws + pk_off);
    unsigned* A2     = (unsigned*)((char*)d_ws + a2_off);
    unsigned* B2     = (unsigned*)((char*)d_ws + b2_off);

    // Hash level 3 + prep (64 tail blocks: packed01, A2/B2, wt).
    hash3_prep_kernel<<<blocks1 + 64, 256, 0, stream>>>(
        x, gtab, feat + (size_t)0 * N, N, wt, packed, A2, B2, W0, b0, W1, b1);
    hash_level_kernel<<<blocks1, 256, 0, stream>>>(
        x, gtab + 823296u, feat + (size_t)1 * N, 255.0f, N);
    hash_level_kernel<<<blocks1, 256, 0, stream>>>(
        x, gtab + 1347584u, feat + (size_t)2 * N, 511.0f, N);

    // Gate the 144KB-LDS path on what the runtime actually permits
    // (host-side queries: deterministic, graph-capture-safe).
    const size_t bigShm = 36864u * 4u;           // 147456 B
    const void* bigK =
        reinterpret_cast<const void*>(&dense_mlp_kernel<1024, true>);
    (void)hipFuncSetAttribute(bigK,
        hipFuncAttributeMaxDynamicSharedMemorySize, (int)bigShm);
    bool big = false;
    hipFuncAttributes fa{};
    if (hipFuncGetAttributes(&fa, bigK) == hipSuccess)
        big = ((size_t)fa.maxDynamicSharedSizeBytes >= bigShm);

    if (big) {
        const int blocksB = (N + 4095) / 4096;   // 1024 thr x 4 pts
        dense_mlp_kernel<1024, true><<<blocksB, 1024, bigShm, stream>>>(
            x, (const float*)grid, feat, wt, packed, A2, B2, out, N);
    } else {
        const int blocksF = (N + 1023) / 1024;   // 256 thr x 4 pts
        dense_mlp_kernel<256, false><<<blocksF, 256, 4096u * 4u, stream>>>(
            x, (const float*)grid, feat, wt, packed, A2, B2, out, N);
    }
}